// Round 1
// 3263.763 us; speedup vs baseline: 1.6194x; 1.6194x over previous
//
#include <hip/hip_runtime.h>
#include <math.h>

// ============================================================================
// Persistent per-signal FFT solver.
//
// Math: per signal r, with A = S@IDCT (orthonormal rows, A A^T = I, P = A^T A):
//   ISTA: s_{t+1} = soft(u_t, 0.05);  u_{t+1} = u_t - 0.05*(I-P)*h_t,
//   h_t = clamp(20*u_t, -1, 1), u_0 = A^T b = 100*DCT(scatter(x[idxs])).
//   (invariant P u_t = A^T b makes this exact; same recurrence the previous
//    GEMM kernel implemented with g = v + c.)
//   Output = 0.01 * IDCT(F'), F' = u_99 - 0.05*clamp(20*u_99)  (= s_100).
//
// P*h per iteration = DCT2(mask(IDCT(h))) via two 2048-pt complex FFTs:
//   IDCT (DCT-III, Makhoul): X'[0]=2*c0*H0, X'[k]=cN*Hk;
//     V[k] = 0.5*e^{+i pi k/2N} (X'[k] - i X'[N-k]);  y = FFT+(V) (real);
//     x[2n]=y[n], x[2n+1]=y[N-1-n].
//   DCT-II: y2[n]=w[2n], y2[N-1-n]=w[2n+1]; Y = FFT-(y2);
//     C[k] = cos(pi k/2N)*ReY + sin(pi k/2N)*ImY;  u[k] = ck*C[k].
// FFT+ is radix-4 DIF (stages L=2048..8, then R2), output digit-reversed;
// FFT- is radix-4 DIT (R2, then L=8..2048), input digit-reversed with the
// SAME permutation => the even/odd reorder + gather/scatter at idxs collapse
// into one precomputed bitmask applied between the FFTs. No reorder passes.
//
// perm(slot p) = t0 +4t1 +16t2 +64t3 +256t4 +1024t5 for
//   p = t0*512 + t1*128 + t2*32 + t3*8 + t4*2 + t5   (t0..t4 radix4, t5 radix2)
// ============================================================================

#define NFT 2048
#define SPW 4            // signals per workgroup; grid = 3072/4 = 768
#define PIF 3.14159265358979323846f
#define C0F 0.022097086912079608f      // sqrt(1/2048)
#define TWOC0 0.044194173824159216f    // 2*sqrt(1/2048)
#define CNF 0.03125f                   // sqrt(2/2048)

__device__ __forceinline__ int load_idx(const int* p, int j) {
    return (p[1] == 0) ? p[2 * j] : p[j];   // int64 (lo,0 pairs) or int32
}
__device__ __forceinline__ int padi(int n) { return n + (n >> 4); }  // LDS pad
__device__ __forceinline__ int pinv(int n) {   // index -> slot
    return ((n & 3) << 9) | (((n >> 2) & 3) << 7) | (((n >> 4) & 3) << 5)
         | (((n >> 6) & 3) << 3) | (((n >> 8) & 3) << 1) | ((n >> 10) & 1);
}
__device__ __forceinline__ int permf(int p) {  // slot -> index
    return ((p >> 9) & 3) | (((p >> 7) & 3) << 2) | (((p >> 5) & 3) << 4)
         | (((p >> 3) & 3) << 6) | (((p >> 1) & 3) << 8) | ((p & 1) << 10);
}
__device__ __forceinline__ float clamp20(float g) {
    return fminf(fmaxf(20.f * g, -1.f), 1.f);
}
__device__ __forceinline__ float2 cadd(float2 a, float2 b) { return make_float2(a.x + b.x, a.y + b.y); }
__device__ __forceinline__ float2 csub(float2 a, float2 b) { return make_float2(a.x - b.x, a.y - b.y); }
__device__ __forceinline__ float2 cmul(float2 a, float2 b) {
    return make_float2(a.x * b.x - a.y * b.y, a.x * b.y + a.y * b.x);
}

// DIF (sign +) stages qb=7,5,3,1 then the final radix-2 (len 2) stage.
__device__ __forceinline__ void dif_tail(float2* wk, const float2* tw, int tid) {
#pragma unroll
    for (int qb = 7; qb >= 1; qb -= 2) {
        const int Q = 1 << qb;
        const int j = tid & (Q - 1);
        const int i0 = ((tid >> qb) << (qb + 2)) | j;
        float2 a = wk[padi(i0)];
        float2 b = wk[padi(i0 + Q)];
        float2 c = wk[padi(i0 + 2 * Q)];
        float2 d = wk[padi(i0 + 3 * Q)];
        float2 A = cadd(a, c), C = csub(a, c);
        float2 B = cadd(b, d), D = csub(b, d);
        float2 iD = make_float2(-D.y, D.x);          // +i*D
        float2 w = tw[j << (9 - qb)];                // e^{+2pi i m/2048}
        float2 w2 = make_float2(w.x * w.x - w.y * w.y, 2.f * w.x * w.y);
        float2 w3 = cmul(w, w2);
        wk[padi(i0)]         = cadd(A, B);
        wk[padi(i0 + Q)]     = cmul(cadd(C, iD), w);
        wk[padi(i0 + 2 * Q)] = cmul(csub(A, B), w2);
        wk[padi(i0 + 3 * Q)] = cmul(csub(C, iD), w3);
        __syncthreads();
    }
#pragma unroll
    for (int h = 0; h < 2; ++h) {                    // R2: pairs (2b,2b+1)
        const int i = (tid + (h << 9)) << 1;
        float2 a = wk[padi(i)], c = wk[padi(i + 1)];
        wk[padi(i)]     = cadd(a, c);
        wk[padi(i + 1)] = csub(a, c);
    }
    __syncthreads();
}

// First DIF stage (qb=9, i0=tid, j=tid) fused with the DCT-III V-build.
// VMODE 0: H = clamp20(g)  (iteration);  VMODE 1: H = g - 0.05*clamp20(g) (final F').
template <int VMODE>
__device__ __forceinline__ void dif_head(float2* wk, const float2* tw, const float* g,
                                         int tid, const float* cc4, const float* sc4) {
    float2 v[4];
#pragma unroll
    for (int q = 0; q < 4; ++q) {
        const int k = tid + (q << 9);
        const int kN = (NFT - k) & (NFT - 1);
        float a0 = g[k], a1 = g[kN];
        float hk, hN;
        if (VMODE == 0) { hk = clamp20(a0);                 hN = clamp20(a1); }
        else            { hk = a0 - 0.05f * clamp20(a0);    hN = a1 - 0.05f * clamp20(a1); }
        float Xk = (k == 0) ? (TWOC0 * hk) : (CNF * hk);
        float XN = (k == 0) ? 0.f : (CNF * hN);             // X'[N] == 0
        // V[k] = 0.5*e^{+i th}(X'k - i X'N) ; th = pi k/4096
        v[q] = make_float2(0.5f * (Xk * cc4[q] + XN * sc4[q]),
                           0.5f * (Xk * sc4[q] - XN * cc4[q]));
    }
    float2 A = cadd(v[0], v[2]), C = csub(v[0], v[2]);
    float2 B = cadd(v[1], v[3]), D = csub(v[1], v[3]);
    float2 iD = make_float2(-D.y, D.x);
    float2 w = tw[tid];
    float2 w2 = make_float2(w.x * w.x - w.y * w.y, 2.f * w.x * w.y);
    float2 w3 = cmul(w, w2);
    wk[padi(tid)]        = cadd(A, B);
    wk[padi(tid + 512)]  = cmul(cadd(C, iD), w);
    wk[padi(tid + 1024)] = cmul(csub(A, B), w2);
    wk[padi(tid + 1536)] = cmul(csub(C, iD), w3);
    __syncthreads();
    dif_tail(wk, tw, tid);
}

// DIT (sign -): R2 stage fused with the measurement mask (Re kept at measured
// slots, everything else zeroed), stages qb=1..7, and the last stage (qb=9)
// fused with the DCT-II epilogue + g update.
// INIT=true: g[k] = u[k];  INIT=false: g[k] += 0.05*(u[k] - clamp20(g[k])).
template <bool INIT>
__device__ __forceinline__ void dit_fused(float2* wk, const float2* tw, float* g, int tid,
                                          const float* cc4, const float* sc4, const float* kR2) {
#pragma unroll
    for (int h = 0; h < 2; ++h) {                    // R2 + mask
        const int i = (tid + (h << 9)) << 1;
        float2 za = wk[padi(i)], zc = wk[padi(i + 1)];
        float ax = za.x * kR2[2 * h];
        float cx = zc.x * kR2[2 * h + 1];
        wk[padi(i)]     = make_float2(ax + cx, 0.f);
        wk[padi(i + 1)] = make_float2(ax - cx, 0.f);
    }
    __syncthreads();
#pragma unroll
    for (int qb = 1; qb <= 7; qb += 2) {
        const int Q = 1 << qb;
        const int j = tid & (Q - 1);
        const int i0 = ((tid >> qb) << (qb + 2)) | j;
        float2 w = tw[j << (9 - qb)]; w.y = -w.y;    // e^{-2pi i m/2048}
        float2 w2 = make_float2(w.x * w.x - w.y * w.y, 2.f * w.x * w.y);
        float2 w3 = cmul(w, w2);
        float2 v0 = wk[padi(i0)];
        float2 v1 = cmul(wk[padi(i0 + Q)], w);
        float2 v2 = cmul(wk[padi(i0 + 2 * Q)], w2);
        float2 v3 = cmul(wk[padi(i0 + 3 * Q)], w3);
        float2 A = cadd(v0, v2), C = csub(v0, v2);
        float2 B = cadd(v1, v3), D = csub(v1, v3);
        float2 miD = make_float2(D.y, -D.x);         // -i*D
        wk[padi(i0)]         = cadd(A, B);
        wk[padi(i0 + Q)]     = cadd(C, miD);
        wk[padi(i0 + 2 * Q)] = csub(A, B);
        wk[padi(i0 + 3 * Q)] = csub(C, miD);
        __syncthreads();
    }
    {   // qb = 9 final stage, results land on this thread's own k = tid+512q
        float2 w = tw[tid]; w.y = -w.y;
        float2 w2 = make_float2(w.x * w.x - w.y * w.y, 2.f * w.x * w.y);
        float2 w3 = cmul(w, w2);
        float2 v0 = wk[padi(tid)];
        float2 v1 = cmul(wk[padi(tid + 512)], w);
        float2 v2 = cmul(wk[padi(tid + 1024)], w2);
        float2 v3 = cmul(wk[padi(tid + 1536)], w3);
        float2 A = cadd(v0, v2), C = csub(v0, v2);
        float2 B = cadd(v1, v3), D = csub(v1, v3);
        float2 miD = make_float2(D.y, -D.x);
        float2 y[4];
        y[0] = cadd(A, B);
        y[1] = cadd(C, miD);
        y[2] = csub(A, B);
        y[3] = csub(C, miD);
#pragma unroll
        for (int q = 0; q < 4; ++q) {
            const int k = tid + (q << 9);
            float Cv = y[q].x * cc4[q] + y[q].y * sc4[q];
            float u = ((k == 0) ? C0F : CNF) * Cv;
            if (INIT) g[k] = u;
            else { float gk = g[k]; g[k] = gk + 0.05f * (u - clamp20(gk)); }
        }
    }
}

__global__ void __launch_bounds__(512, 6) ista_fft_kernel(
    const float* __restrict__ x, const int* __restrict__ idxs,
    float* __restrict__ out) {
    __shared__ float2 wk[2176];          // 2048 + pad(>>4), 17408 B
    __shared__ float gbuf[NFT];          // 8192 B (one signal at a time)
    __shared__ float2 tw[512];           // 4096 B  e^{+2pi i j/2048}
    __shared__ unsigned mbm[64];         // 256 B measurement bitmask (slot space)

    const int tid = threadIdx.x;

    {   // twiddle table (precise trig, built once)
        float ang = PIF * (float)tid * (1.0f / 1024.0f);
        tw[tid] = make_float2(cosf(ang), sinf(ang));
    }
    if (tid < 64) mbm[tid] = 0u;
    __syncthreads();
    {   // measured x-index -> y-index -> slot; set mask bit
        int idx = load_idx(idxs, tid);
        int yid = (idx & 1) ? (2047 - (idx >> 1)) : (idx >> 1);
        int p = pinv(yid);
        atomicOr(&mbm[p >> 5], 1u << (p & 31));
    }
    __syncthreads();

    // per-thread constants, invariant over signals and iterations
    float cc4[4], sc4[4], kR2[4];
#pragma unroll
    for (int q = 0; q < 4; ++q) {
        float sv, cv;
        sincosf(PIF * (float)(tid + (q << 9)) * (1.0f / 4096.0f), &sv, &cv);
        sc4[q] = sv; cc4[q] = cv;
    }
#pragma unroll
    for (int h = 0; h < 2; ++h) {
        int p0 = (tid + (h << 9)) << 1;
        kR2[2 * h]     = (float)((mbm[p0 >> 5] >> (p0 & 31)) & 1u);
        kR2[2 * h + 1] = (float)((mbm[(p0 + 1) >> 5] >> ((p0 + 1) & 31)) & 1u);
    }

    const int sig0 = blockIdx.x * SPW;
#pragma unroll 1
    for (int s = 0; s < SPW; ++s) {
        const int r = sig0 + s;
        float* g = gbuf;
        __syncthreads();                         // wk reuse across signals
        // ---- init: wk = scatter(100*x[r, idxs]) in slot space ----
#pragma unroll
        for (int q = 0; q < 5; ++q) {
            int n = tid + (q << 9);
            if (n < 2176) wk[n] = make_float2(0.f, 0.f);
        }
        __syncthreads();
        {
            int idx = load_idx(idxs, tid);
            int yid = (idx & 1) ? (2047 - (idx >> 1)) : (idx >> 1);
            int p = pinv(yid);
            float val = 100.f * x[(size_t)r * NFT + idx];
            wk[padi(p)] = make_float2(val, 0.f);
        }
        __syncthreads();
        dit_fused<true>(wk, tw, g, tid, cc4, sc4, kR2);   // g = u_0 = A^T b

        // ---- 99 iterations: u += 0.05*(P h - h) ----
#pragma unroll 1
        for (int it = 0; it < 99; ++it) {
            __syncthreads();                     // g cross-thread (k<->N-k)
            dif_head<0>(wk, tw, g, tid, cc4, sc4);          // IDCT(h)
            dit_fused<false>(wk, tw, g, tid, cc4, sc4, kR2); // mask,DCT,update
        }

        // ---- final: out = 0.01 * IDCT(F'), F' = soft(u_99) ----
        __syncthreads();
        dif_head<1>(wk, tw, g, tid, cc4, sc4);
#pragma unroll
        for (int q = 0; q < 4; ++q) {
            const int p = tid + (q << 9);
            const int m = permf(p);                         // y-index
            const int i = (m < 1024) ? (m << 1) : (4095 - (m << 1));
            out[(size_t)r * NFT + i] = 0.01f * wk[padi(p)].x;
        }
    }
}

extern "C" void kernel_launch(void* const* d_in, const int* in_sizes, int n_in,
                              void* d_out, int out_size, void* d_ws, size_t ws_size,
                              hipStream_t stream) {
    (void)in_sizes; (void)n_in; (void)out_size; (void)d_ws; (void)ws_size;
    const float* x = (const float*)d_in[0];
    const int* idxs = (const int*)d_in[1];
    ista_fft_kernel<<<dim3(3072 / SPW), dim3(512), 0, stream>>>(x, idxs, (float*)d_out);
}